// Round 1
// baseline (113.598 us; speedup 1.0000x reference)
//
#include <hip/hip_runtime.h>
#include <hip/hip_bf16.h>

#define KBINS 8
#define DDIM 2048
#define BROWS 4096
#define NPAR (3 * KBINS + 1)   // 25
#define ROWS_PER_BLOCK 16

__device__ __forceinline__ float fast_rcp(float a) {
    float r = __builtin_amdgcn_rcpf(a);
    // one Newton-Raphson step -> ~1 ulp
    r = r * (2.0f - a * r);
    return r;
}

// ws layout (floats): xk[9][D], yk[9][D], sl[9][D]
__global__ __launch_bounds__(256) void normalize_params_kernel(
        const float* __restrict__ params, float* __restrict__ tab) {
    const int d = blockIdx.x * blockDim.x + threadIdx.x;
    if (d >= DDIM) return;
    const float* p = params + d * NPAR;

    const float RMIN = -5.0f, RMAX = 5.0f;
    const float MIN_BIN = 1e-3f, MIN_SLOPE = 1e-3f, MAX_SLOPE = 10.0f;
    const float remaining = (RMAX - RMIN) - KBINS * MIN_BIN;  // 9.992

    float wsig[KBINS], hsig[KBINS];
    float wsum = 0.0f, hsum = 0.0f;
#pragma unroll
    for (int k = 0; k < KBINS; ++k) {
        wsig[k] = 1.0f / (1.0f + expf(-p[k]));
        wsum += wsig[k];
    }
#pragma unroll
    for (int k = 0; k < KBINS; ++k) {
        hsig[k] = 1.0f / (1.0f + expf(-p[KBINS + k]));
        hsum += hsig[k];
    }
    const float wscale = remaining / wsum;
    const float hscale = remaining / hsum;

    float* xk_t = tab;
    float* yk_t = tab + (KBINS + 1) * DDIM;
    float* sl_t = tab + 2 * (KBINS + 1) * DDIM;

    xk_t[d] = RMIN;
    yk_t[d] = RMIN;
    float cx = RMIN, cy = RMIN;
#pragma unroll
    for (int k = 0; k < KBINS; ++k) {
        cx += MIN_BIN + wsig[k] * wscale;
        cy += MIN_BIN + hsig[k] * hscale;
        xk_t[(k + 1) * DDIM + d] = cx;
        yk_t[(k + 1) * DDIM + d] = cy;
    }
#pragma unroll
    for (int k = 0; k <= KBINS; ++k) {
        float sr = p[2 * KBINS + k];
        sl_t[k * DDIM + d] = MIN_SLOPE + (MAX_SLOPE - MIN_SLOPE) / (1.0f + expf(-sr));
    }
}

__global__ __launch_bounds__(256) void rqs_kernel(
        const float* __restrict__ x_in, const float* __restrict__ tab,
        float* __restrict__ y_out, float* __restrict__ logdet) {
    const int d = (blockIdx.x & 7) * 256 + (int)threadIdx.x;  // 8 d-chunks of 256
    const int b0 = (int)(blockIdx.x >> 3) * ROWS_PER_BLOCK;

    const float RMIN = -5.0f, RMAX = 5.0f;

    const float* xk_t = tab;
    const float* yk_t = tab + (KBINS + 1) * DDIM;
    const float* sl_t = tab + 2 * (KBINS + 1) * DDIM;

    // preload knot tables into registers (coalesced: [k][D] layout)
    float xk[KBINS + 1], yk[KBINS + 1], sl[KBINS + 1];
#pragma unroll
    for (int k = 0; k <= KBINS; ++k) {
        xk[k] = xk_t[k * DDIM + d];
        yk[k] = yk_t[k * DDIM + d];
        sl[k] = sl_t[k * DDIM + d];
    }
    float wd[KBINS], hd[KBINS];
#pragma unroll
    for (int k = 0; k < KBINS; ++k) {
        wd[k] = xk[k + 1] - xk[k];
        hd[k] = yk[k + 1] - yk[k];
    }
    const float log_s0 = __logf(sl[0]);
    const float log_sK = __logf(sl[KBINS]);

    for (int r = 0; r < ROWS_PER_BLOCK; ++r) {
        const int b = b0 + r;
        const int idx = b * DDIM + d;
        const float x = x_in[idx];

        // branchless bin select: bin = #{j in 1..K-1 : xk[j] <= x}
        float x_k = xk[0], w = wd[0], y_k = yk[0], h = hd[0];
        float dk = sl[0], dk1 = sl[1];
#pragma unroll
        for (int j = 1; j < KBINS; ++j) {
            const bool c = xk[j] <= x;
            x_k = c ? xk[j] : x_k;
            w   = c ? wd[j] : w;
            y_k = c ? yk[j] : y_k;
            h   = c ? hd[j] : h;
            dk  = c ? sl[j] : dk;
            dk1 = c ? sl[j + 1] : dk1;
        }

        const float inv_w = fast_rcp(w);
        const float xi  = (x - x_k) * inv_w;
        const float s   = h * inv_w;
        const float xi1 = 1.0f - xi;
        const float xx  = xi * xi1;

        const float num = s * xi * xi + dk * xx;
        const float den = s + (dk1 + dk - 2.0f * s) * xx;
        const float inv_den = fast_rcp(den);

        float y  = fmaf(h * num, inv_den, y_k);
        // derivative = s^2 * inner / den^2 ; log avoids the divide
        const float inner = dk1 * xi * xi + 2.0f * s * xx + dk * xi1 * xi1;
        float ld = 2.0f * __logf(s) + __logf(inner) - 2.0f * __logf(den);

        if (x <= RMIN) { y = fmaf(x - RMIN, sl[0], RMIN); ld = log_s0; }
        else if (x >= RMAX) { y = fmaf(x - RMAX, sl[KBINS], RMAX); ld = log_sK; }

        y_out[idx] = y;

        // wave-level reduction of ld, one atomic per wave
        float v = ld;
#pragma unroll
        for (int off = 32; off > 0; off >>= 1) v += __shfl_down(v, off);
        if ((threadIdx.x & 63) == 0) atomicAdd(&logdet[b], v);
    }
}

extern "C" void kernel_launch(void* const* d_in, const int* in_sizes, int n_in,
                              void* d_out, int out_size, void* d_ws, size_t ws_size,
                              hipStream_t stream) {
    const float* x = (const float*)d_in[0];
    const float* params = (const float*)d_in[1];
    float* out = (float*)d_out;
    float* y_out = out;                        // B*D floats
    float* logdet = out + (size_t)BROWS * DDIM; // B floats
    float* tab = (float*)d_ws;                 // 27*D floats = 216 KiB

    hipMemsetAsync(logdet, 0, BROWS * sizeof(float), stream);

    normalize_params_kernel<<<DDIM / 256, 256, 0, stream>>>(params, tab);

    const int grid = 8 * (BROWS / ROWS_PER_BLOCK);  // 2048 blocks
    rqs_kernel<<<grid, 256, 0, stream>>>(x, tab, y_out, logdet);
}

// Round 2
// 100.755 us; speedup vs baseline: 1.1275x; 1.1275x over previous
//
#include <hip/hip_runtime.h>
#include <hip/hip_bf16.h>

#define KBINS 8
#define DDIM 2048
#define BROWS 4096
#define NPAR (3 * KBINS + 1)   // 25
#define ROWS_PER_BLOCK 16

__device__ __forceinline__ float fast_rcp(float a) {
    float r = __builtin_amdgcn_rcpf(a);
    r = r * (2.0f - a * r);   // one NR step
    return r;
}

__device__ __forceinline__ float fsigmoid(float t) {
    return fast_rcp(1.0f + __expf(-t));
}

// Single fused kernel: each block normalizes params for its 256 columns into
// LDS, then processes 16 rows. lt layout: [0..8]=x_knots, [9..17]=y_knots,
// [18..26]=slopes; stride 256 floats -> bank = tid%32 -> conflict-free gather.
__global__ __launch_bounds__(256) void rqs_kernel(
        const float* __restrict__ x_in, const float* __restrict__ params,
        float* __restrict__ y_out, float* __restrict__ logdet) {
    const int tid = (int)threadIdx.x;
    const int d = (blockIdx.x & 7) * 256 + tid;   // 8 d-chunks of 256
    const int b0 = (int)(blockIdx.x >> 3) * ROWS_PER_BLOCK;

    const float RMIN = -5.0f, RMAX = 5.0f;
    const float MIN_BIN = 1e-3f, MIN_SLOPE = 1e-3f, MAX_SLOPE = 10.0f;
    const float remaining = (RMAX - RMIN) - KBINS * MIN_BIN;  // 9.992

    __shared__ float lt[27][256];
    __shared__ float red[ROWS_PER_BLOCK][4];

    // ---- normalize params for column d (redundant per d-chunk, cheap) ----
    const float* p = params + d * NPAR;
    float pr[NPAR];
#pragma unroll
    for (int i = 0; i < NPAR; ++i) pr[i] = p[i];

    float ws[KBINS], hs[KBINS], sl[KBINS + 1];
    float wsum = 0.0f, hsum = 0.0f;
#pragma unroll
    for (int k = 0; k < KBINS; ++k) { ws[k] = fsigmoid(pr[k]); wsum += ws[k]; }
#pragma unroll
    for (int k = 0; k < KBINS; ++k) { hs[k] = fsigmoid(pr[KBINS + k]); hsum += hs[k]; }
#pragma unroll
    for (int k = 0; k <= KBINS; ++k)
        sl[k] = MIN_SLOPE + (MAX_SLOPE - MIN_SLOPE) * fsigmoid(pr[2 * KBINS + k]);

    const float wscale = remaining * fast_rcp(wsum);
    const float hscale = remaining * fast_rcp(hsum);

    lt[0][tid] = RMIN;
    lt[9][tid] = RMIN;
    float xkr[KBINS];   // xkr[1..7] = interior knots for binning
    float cx = RMIN, cy = RMIN;
#pragma unroll
    for (int k = 0; k < KBINS; ++k) {
        cx += MIN_BIN + ws[k] * wscale;
        cy += MIN_BIN + hs[k] * hscale;
        lt[1 + k][tid] = cx;
        lt[10 + k][tid] = cy;
        if (k < KBINS - 1) xkr[k + 1] = cx;
    }
#pragma unroll
    for (int k = 0; k <= KBINS; ++k) lt[18 + k][tid] = sl[k];

    const float s0 = sl[0], sK = sl[KBINS];
    const float log_s0 = __logf(s0), log_sK = __logf(sK);
    __syncthreads();

    // ---- main: 16 rows ----
    float xv[ROWS_PER_BLOCK];
#pragma unroll
    for (int r = 0; r < ROWS_PER_BLOCK; ++r)
        xv[r] = x_in[(size_t)(b0 + r) * DDIM + d];

    float ldv[ROWS_PER_BLOCK];
#pragma unroll
    for (int r = 0; r < ROWS_PER_BLOCK; ++r) {
        const float x = xv[r];
        int bin = 0;
#pragma unroll
        for (int j = 1; j < KBINS; ++j) bin += (xkr[j] <= x) ? 1 : 0;

        const float x_k  = lt[bin][tid];
        const float x_k1 = lt[bin + 1][tid];
        const float y_k  = lt[9 + bin][tid];
        const float y_k1 = lt[10 + bin][tid];
        const float dk   = lt[18 + bin][tid];
        const float dk1  = lt[19 + bin][tid];

        const float w = x_k1 - x_k;
        const float h = y_k1 - y_k;
        const float inv_w = fast_rcp(w);
        const float xi  = (x - x_k) * inv_w;
        const float s   = h * inv_w;
        const float xi1 = 1.0f - xi;
        const float xx  = xi * xi1;

        const float num = s * xi * xi + dk * xx;
        const float den = s + (dk1 + dk - 2.0f * s) * xx;
        const float inv_den = fast_rcp(den);

        const float y_sp = fmaf(h * num, inv_den, y_k);
        const float inner = dk1 * xi * xi + 2.0f * s * xx + dk * xi1 * xi1;
        const float t = s * inv_den;
        const float der = t * t * inner;

        const bool below = x <= RMIN;
        const bool above = x >= RMAX;
        float y  = below ? fmaf(x - RMIN, s0, RMIN)
                 : above ? fmaf(x - RMAX, sK, RMAX) : y_sp;
        float ld = below ? log_s0 : above ? log_sK : __logf(der);

        y_out[(size_t)(b0 + r) * DDIM + d] = y;
        ldv[r] = ld;
    }

    // ---- reduction: 16 independent butterfly chains (latency-pipelined) ----
#pragma unroll
    for (int off = 32; off > 0; off >>= 1) {
#pragma unroll
        for (int r = 0; r < ROWS_PER_BLOCK; ++r)
            ldv[r] += __shfl_down(ldv[r], off);
    }
    const int wid = tid >> 6, lane = tid & 63;
    if (lane == 0) {
#pragma unroll
        for (int r = 0; r < ROWS_PER_BLOCK; ++r) red[r][wid] = ldv[r];
    }
    __syncthreads();
    if (wid == 0) {
        float v = red[lane >> 2][lane & 3];
        v += __shfl_down(v, 1);
        v += __shfl_down(v, 2);
        if ((lane & 3) == 0) atomicAdd(&logdet[b0 + (lane >> 2)], v);
    }
}

extern "C" void kernel_launch(void* const* d_in, const int* in_sizes, int n_in,
                              void* d_out, int out_size, void* d_ws, size_t ws_size,
                              hipStream_t stream) {
    const float* x = (const float*)d_in[0];
    const float* params = (const float*)d_in[1];
    float* out = (float*)d_out;
    float* y_out = out;                          // B*D floats
    float* logdet = out + (size_t)BROWS * DDIM;  // B floats

    hipMemsetAsync(logdet, 0, BROWS * sizeof(float), stream);

    const int grid = 8 * (BROWS / ROWS_PER_BLOCK);  // 2048 blocks
    rqs_kernel<<<grid, 256, 0, stream>>>(x, params, y_out, logdet);
}